// Round 6
// baseline (169.102 us; speedup 1.0000x reference)
//
#include <hip/hip_runtime.h>
#include <hip/hip_bf16.h>
#include <cstdint>

// ---------- types / helpers ----------
typedef __attribute__((ext_vector_type(8))) short  short8;
typedef __attribute__((ext_vector_type(8))) __bf16 bf16x8;
typedef __attribute__((ext_vector_type(4))) float  floatx4;
typedef __attribute__((ext_vector_type(4))) float  f32x4;
typedef __attribute__((ext_vector_type(4))) short  short4v;

union Frag { short8 s; bf16x8 b; };

__device__ inline short f2bf(float f) {
    union { float f; unsigned u; } v; v.f = f;
    unsigned r = (v.u + 0x7fffu + ((v.u >> 16) & 1u)) >> 16;  // RNE
    return (short)r;
}
__device__ inline float elu(float x) { return x > 0.f ? x : __expf(x) - 1.f; }

__device__ inline short8 load8_f32_to_bf16(const float* __restrict__ p) {
    float4 f0 = ((const float4*)p)[0];
    float4 f1 = ((const float4*)p)[1];
    short8 r;
    r[0] = f2bf(f0.x); r[1] = f2bf(f0.y); r[2] = f2bf(f0.z); r[3] = f2bf(f0.w);
    r[4] = f2bf(f1.x); r[5] = f2bf(f1.y); r[6] = f2bf(f1.z); r[7] = f2bf(f1.w);
    return r;
}

// ---------- constants ----------
#define B_SZ   4096
#define Z_DIM  256
#define H_DIM  1024
#define OUT_W  33
// option packing offsets (SIZES = [16384,64,4096,64,2048,32])
#define OFF_W1 0
#define OFF_B1 16384
#define OFF_W2 16448
#define OFF_B2 20544
#define OFF_W3 20608
#define OFF_B3 22656
#define OPT_W  22688

#define G1_BLOCKS 256               // gemm1 128x128 tiles: 32 x 8
#define CONV_BLOCKS 64
#define HYP_BLOCKS (B_SZ / 4)       // all 4096 samples, 4 waves/block

// ---------- MFMA gemm tile: block = (32*SM) x (32*SN), 4 waves 2x2 ----------
// Wave computes (16*SM) x (16*SN) via SM x SN frags of 16x16x32.
template<int KTOT, int SM, int SN, bool ACONV, bool BCONV, bool VEPI>
__device__ __forceinline__ void gemm_tile(
    const void* __restrict__ Av, const void* __restrict__ Bv,
    const float* __restrict__ bias, const float* __restrict__ w3,
    __hip_bfloat16* __restrict__ T, float* __restrict__ out,
    int bm, int bn, int tid)
{
    const int lane = tid & 63, wid = tid >> 6;
    const int wm = wid >> 1, wn = wid & 1;
    const int m_wave = bm * (32 * SM) + wm * (16 * SM);
    const int n_wave = bn * (32 * SN) + wn * (16 * SN);
    const int lr = lane & 15, lk = (lane >> 4) * 8;

    floatx4 acc[SM][SN] = {};
    for (int k0 = 0; k0 < KTOT; k0 += 32) {
        Frag a[SM], bb[SN];
#pragma unroll
        for (int sm = 0; sm < SM; ++sm) {
            const size_t off = (size_t)(m_wave + sm * 16 + lr) * KTOT + k0 + lk;
            if constexpr (ACONV) a[sm].s = load8_f32_to_bf16((const float*)Av + off);
            else                 a[sm].s = *(const short8*)((const ushort*)Av + off);
        }
#pragma unroll
        for (int sn = 0; sn < SN; ++sn) {
            const size_t off = (size_t)(n_wave + sn * 16 + lr) * KTOT + k0 + lk;
            if constexpr (BCONV) bb[sn].s = load8_f32_to_bf16((const float*)Bv + off);
            else                 bb[sn].s = *(const short8*)((const ushort*)Bv + off);
        }
#pragma unroll
        for (int sm = 0; sm < SM; ++sm)
#pragma unroll
            for (int sn = 0; sn < SN; ++sn)
                acc[sm][sn] = __builtin_amdgcn_mfma_f32_16x16x32_bf16(
                    a[sm].b, bb[sn].b, acc[sm][sn], 0, 0, 0);
    }

    if constexpr (VEPI) {
        float bias_v[SN], w3_v[SN];
#pragma unroll
        for (int sn = 0; sn < SN; ++sn) {
            const int n = n_wave + sn * 16 + lr;
            bias_v[sn] = bias[n];
            w3_v[sn]   = w3[n];
        }
#pragma unroll
        for (int sm = 0; sm < SM; ++sm) {
#pragma unroll
            for (int r = 0; r < 4; ++r) {
                float rowsum = 0.f;
#pragma unroll
                for (int sn = 0; sn < SN; ++sn)
                    rowsum += elu(acc[sm][sn][r] + bias_v[sn]) * w3_v[sn];
                rowsum += __shfl_xor(rowsum, 1);
                rowsum += __shfl_xor(rowsum, 2);
                rowsum += __shfl_xor(rowsum, 4);
                rowsum += __shfl_xor(rowsum, 8);
                if (lr == 0) {
                    const int m = m_wave + sm * 16 + (lane >> 4) * 4 + r;
                    atomicAdd(out + (size_t)m * OUT_W, rowsum);
                }
            }
        }
    } else {
#pragma unroll
        for (int sm = 0; sm < SM; ++sm)
#pragma unroll
            for (int sn = 0; sn < SN; ++sn) {
                const int n = n_wave + sn * 16 + lr;
                const float bv = bias[n];
#pragma unroll
                for (int r = 0; r < 4; ++r) {
                    const int m = m_wave + sm * 16 + (lane >> 4) * 4 + r;
                    T[(size_t)m * H_DIM + n] = __float2bfloat16(elu(acc[sm][sn][r] + bv));
                }
            }
    }
}

// ---------- hypernet: one wave per sample, barrier-free, single-buffered ----------
__device__ __forceinline__ void hyper_wave(
    const float* __restrict__ z, const float* __restrict__ opt,
    float* __restrict__ out, int b, int lane,
    float* __restrict__ h1, float* __restrict__ h2)
{
    const float* __restrict__ orow = opt + (size_t)b * OPT_W;

    const f32x4 z4 = *(const f32x4*)(z + (size_t)b * Z_DIM + 4 * lane);

    // ---- layer 1: [64,256] @ z -> h1, relu. 4 chunks of 16 rows ----
    {
        const f32x4* W = (const f32x4*)(orow + OFF_W1);
#pragma unroll
        for (int c = 0; c < 4; ++c) {
            f32x4 wv[16];
#pragma unroll
            for (int j = 0; j < 16; ++j)
                wv[j] = W[(c * 16 + j) * 64 + lane];
#pragma unroll
            for (int j = 0; j < 16; ++j) {
                float p = wv[j].x * z4.x + wv[j].y * z4.y +
                          wv[j].z * z4.z + wv[j].w * z4.w;
                p += __shfl_xor(p, 1);  p += __shfl_xor(p, 2);
                p += __shfl_xor(p, 4);  p += __shfl_xor(p, 8);
                p += __shfl_xor(p, 16); p += __shfl_xor(p, 32);
                const int r = c * 16 + j;
                if (lane == 0)
                    h1[r] = fmaxf(p + orow[OFF_B1 + r], 0.f);
            }
        }
    }

    // ---- layer 2: [64,64] @ h1 -> h2, relu ----
    {
        const f32x4 h1v = *(const f32x4*)(h1 + 4 * (lane & 15));
        const f32x4* W = (const f32x4*)(orow + OFF_W2);
        f32x4 wv[16];
#pragma unroll
        for (int j = 0; j < 16; ++j) wv[j] = W[j * 64 + lane];
#pragma unroll
        for (int j = 0; j < 16; ++j) {
            float p = wv[j].x * h1v.x + wv[j].y * h1v.y +
                      wv[j].z * h1v.z + wv[j].w * h1v.w;
            p += __shfl_xor(p, 1); p += __shfl_xor(p, 2);
            p += __shfl_xor(p, 4); p += __shfl_xor(p, 8);
            const int r = j * 4 + (lane >> 4);
            if ((lane & 15) == 0)
                h2[r] = fmaxf(p + orow[OFF_B2 + r], 0.f);
        }
    }

    // ---- layer 3: [32,64] @ h2 -> action ----
    {
        const f32x4 h2v = *(const f32x4*)(h2 + 4 * (lane & 15));
        const f32x4* W = (const f32x4*)(orow + OFF_W3);
        f32x4 wv[8];
#pragma unroll
        for (int j = 0; j < 8; ++j) wv[j] = W[j * 64 + lane];
#pragma unroll
        for (int j = 0; j < 8; ++j) {
            float p = wv[j].x * h2v.x + wv[j].y * h2v.y +
                      wv[j].z * h2v.z + wv[j].w * h2v.w;
            p += __shfl_xor(p, 1); p += __shfl_xor(p, 2);
            p += __shfl_xor(p, 4); p += __shfl_xor(p, 8);
            const int r = j * 4 + (lane >> 4);
            if ((lane & 15) == 0)
                out[(size_t)b * OUT_W + 1 + r] = p + orow[OFF_B3 + r];
        }
    }
}

// ---------- kernel 1: gemm1 + w2conv + col0-init + ALL hyper samples ----------
__global__ __launch_bounds__(256) void k1_kernel(
    const float* __restrict__ z, const float* __restrict__ opt,
    const float* __restrict__ w1, const float* __restrict__ b1,
    const float* __restrict__ w2, const float* __restrict__ b3,
    __hip_bfloat16* __restrict__ T1, __hip_bfloat16* __restrict__ w2bf,
    float* __restrict__ out)
{
    __shared__ float hbuf[4][128];
    const int blk = blockIdx.x, t = threadIdx.x;

    if (blk < G1_BLOCKS) {
        gemm_tile<Z_DIM, 4, 4, true, true, false>(z, w1, b1, nullptr, T1, nullptr,
                                                  blk >> 3, blk & 7, t);
    } else if (blk < G1_BLOCKS + CONV_BLOCKS) {
        const int gtid = (blk - G1_BLOCKS) * 256 + t;  // 0..16383
        if (gtid < B_SZ) out[(size_t)gtid * OUT_W] = b3[0];  // init value col
#pragma unroll
        for (int i = 0; i < 16; ++i) {
            const int v = gtid + i * 16384;           // float4 index < 262144
            float4 f = ((const float4*)w2)[v];
            short4v s;
            s[0] = f2bf(f.x); s[1] = f2bf(f.y); s[2] = f2bf(f.z); s[3] = f2bf(f.w);
            ((short4v*)w2bf)[v] = s;
        }
    } else {
        const int wid = t >> 6, lane = t & 63;
        const int b = (blk - (G1_BLOCKS + CONV_BLOCKS)) * 4 + wid;
        hyper_wave(z, opt, out, b, lane, hbuf[wid], hbuf[wid] + 64);
    }
}

// ---------- kernel 2: gemm2 + value, alone (uncongested) ----------
// 128x64 tiles: 512 blocks = 2/CU, 2 waves/SIMD.
__global__ __launch_bounds__(256) void k2_kernel(
    const __hip_bfloat16* __restrict__ T1, const __hip_bfloat16* __restrict__ w2bf,
    const float* __restrict__ b2, const float* __restrict__ w3,
    float* __restrict__ out)
{
    const int blk = blockIdx.x, t = threadIdx.x;
    gemm_tile<H_DIM, 4, 2, false, false, true>(T1, w2bf, b2, w3, nullptr, out,
                                               blk >> 4, blk & 15, t);
}

// ---------- launcher ----------
extern "C" void kernel_launch(void* const* d_in, const int* in_sizes, int n_in,
                              void* d_out, int out_size, void* d_ws, size_t ws_size,
                              hipStream_t stream)
{
    const float* z   = (const float*)d_in[0];
    const float* opt = (const float*)d_in[1];
    const float* w1  = (const float*)d_in[2];
    const float* b1  = (const float*)d_in[3];
    const float* w2  = (const float*)d_in[4];
    const float* b2  = (const float*)d_in[5];
    const float* w3  = (const float*)d_in[6];
    const float* b3  = (const float*)d_in[7];
    float* out = (float*)d_out;

    __hip_bfloat16* T1   = (__hip_bfloat16*)d_ws;  // 8 MB
    __hip_bfloat16* w2bf = (__hip_bfloat16*)((char*)d_ws +
                             (size_t)B_SZ * H_DIM * sizeof(__hip_bfloat16));  // 2 MB

    k1_kernel<<<dim3(G1_BLOCKS + CONV_BLOCKS + HYP_BLOCKS), dim3(256), 0, stream>>>(
        z, opt, w1, b1, w2, b3, T1, w2bf, out);

    k2_kernel<<<dim3((B_SZ / 128) * (H_DIM / 64)), dim3(256), 0, stream>>>(
        T1, w2bf, b2, w3, out);
}

// Round 7
// 119.952 us; speedup vs baseline: 1.4097x; 1.4097x over previous
//
#include <hip/hip_runtime.h>
#include <hip/hip_bf16.h>
#include <cstdint>

// ---------- types / helpers ----------
typedef __attribute__((ext_vector_type(8))) short  short8;
typedef __attribute__((ext_vector_type(8))) __bf16 bf16x8;
typedef __attribute__((ext_vector_type(4))) float  floatx4;
typedef __attribute__((ext_vector_type(4))) float  f32x4;
typedef __attribute__((ext_vector_type(4))) short  short4v;

union Frag { short8 s; bf16x8 b; };

__device__ inline short f2bf(float f) {
    union { float f; unsigned u; } v; v.f = f;
    unsigned r = (v.u + 0x7fffu + ((v.u >> 16) & 1u)) >> 16;  // RNE
    return (short)r;
}
__device__ inline float elu(float x) { return x > 0.f ? x : __expf(x) - 1.f; }

__device__ inline short8 load8_f32_to_bf16(const float* __restrict__ p) {
    float4 f0 = ((const float4*)p)[0];
    float4 f1 = ((const float4*)p)[1];
    short8 r;
    r[0] = f2bf(f0.x); r[1] = f2bf(f0.y); r[2] = f2bf(f0.z); r[3] = f2bf(f0.w);
    r[4] = f2bf(f1.x); r[5] = f2bf(f1.y); r[6] = f2bf(f1.z); r[7] = f2bf(f1.w);
    return r;
}
__device__ inline float dot4(f32x4 a, f32x4 b) {
    return a.x * b.x + a.y * b.y + a.z * b.z + a.w * b.w;
}

// ---------- constants ----------
#define B_SZ   4096
#define Z_DIM  256
#define H_DIM  1024
#define OUT_W  33
// option packing offsets (SIZES = [16384,64,4096,64,2048,32])
#define OFF_W1 0
#define OFF_B1 16384
#define OFF_W2 16448
#define OFF_B2 20544
#define OFF_W3 20608
#define OFF_B3 22656
#define OPT_W  22688

#define HYP_K1 1024                 // hyper samples done in kernel 1 (R3-proven split)
#define G_BLOCKS 256                // 128x128 tiles: (4096/128) x (1024/128)
#define CONV_BLOCKS 64

// ---------- shared 128x128 MFMA gemm tile (4 waves 2x2, 4x4 frags) ----------
template<int KTOT, bool ACONV, bool BCONV, bool VEPI>
__device__ __forceinline__ void gemm_tile(
    const void* __restrict__ Av, const void* __restrict__ Bv,
    const float* __restrict__ bias, const float* __restrict__ w3,
    __hip_bfloat16* __restrict__ T, float* __restrict__ out,
    int bm, int bn, int tid)
{
    const int lane = tid & 63, wid = tid >> 6;
    const int wm = wid >> 1, wn = wid & 1;
    const int m_wave = bm * 128 + wm * 64;
    const int n_wave = bn * 128 + wn * 64;
    const int lr = lane & 15, lk = (lane >> 4) * 8;

    floatx4 acc[4][4] = {};
    for (int k0 = 0; k0 < KTOT; k0 += 32) {
        Frag a[4], bb[4];
#pragma unroll
        for (int sm = 0; sm < 4; ++sm) {
            const size_t off = (size_t)(m_wave + sm * 16 + lr) * KTOT + k0 + lk;
            if constexpr (ACONV) a[sm].s = load8_f32_to_bf16((const float*)Av + off);
            else                 a[sm].s = *(const short8*)((const ushort*)Av + off);
        }
#pragma unroll
        for (int sn = 0; sn < 4; ++sn) {
            const size_t off = (size_t)(n_wave + sn * 16 + lr) * KTOT + k0 + lk;
            if constexpr (BCONV) bb[sn].s = load8_f32_to_bf16((const float*)Bv + off);
            else                 bb[sn].s = *(const short8*)((const ushort*)Bv + off);
        }
#pragma unroll
        for (int sm = 0; sm < 4; ++sm)
#pragma unroll
            for (int sn = 0; sn < 4; ++sn)
                acc[sm][sn] = __builtin_amdgcn_mfma_f32_16x16x32_bf16(
                    a[sm].b, bb[sn].b, acc[sm][sn], 0, 0, 0);
    }

    if constexpr (VEPI) {
        float bias_v[4], w3_v[4];
#pragma unroll
        for (int sn = 0; sn < 4; ++sn) {
            const int n = n_wave + sn * 16 + lr;
            bias_v[sn] = bias[n];
            w3_v[sn]   = w3[n];
        }
#pragma unroll
        for (int sm = 0; sm < 4; ++sm) {
#pragma unroll
            for (int r = 0; r < 4; ++r) {
                float rowsum = 0.f;
#pragma unroll
                for (int sn = 0; sn < 4; ++sn)
                    rowsum += elu(acc[sm][sn][r] + bias_v[sn]) * w3_v[sn];
                rowsum += __shfl_xor(rowsum, 1);
                rowsum += __shfl_xor(rowsum, 2);
                rowsum += __shfl_xor(rowsum, 4);
                rowsum += __shfl_xor(rowsum, 8);
                if (lr == 0) {
                    const int m = m_wave + sm * 16 + (lane >> 4) * 4 + r;
                    atomicAdd(out + (size_t)m * OUT_W, rowsum);
                }
            }
        }
    } else {
#pragma unroll
        for (int sm = 0; sm < 4; ++sm)
#pragma unroll
            for (int sn = 0; sn < 4; ++sn) {
                const int n = n_wave + sn * 16 + lr;
                const float bv = bias[n];
#pragma unroll
                for (int r = 0; r < 4; ++r) {
                    const int m = m_wave + sm * 16 + (lane >> 4) * 4 + r;
                    T[(size_t)m * H_DIM + n] = __float2bfloat16(elu(acc[sm][sn][r] + bv));
                }
            }
    }
}

// ---------- hypernet: block-per-sample (R3 structure), DPP-only reduces ----------
// Layer 1 rewritten: lane accumulates over K in registers (4 passes of 64
// cols), ONE 4-level xor(1,2,4,8) reduce per 4-row group. No ds_bpermute.
__device__ __forceinline__ void hyper_sample(
    const float* __restrict__ z, const float* __restrict__ opt,
    float* __restrict__ out, int b, int tid,
    float* __restrict__ h1, float* __restrict__ h2)
{
    const int lane = tid & 63, w = tid >> 6;
    const int l16 = lane & 15, lg = lane >> 4;
    const float* __restrict__ orow = opt + (size_t)b * OPT_W;

    // preload z slices: zv[p] = z[b][64p + 4*l16 .. +3]
    const f32x4* __restrict__ Z4 = (const f32x4*)(z + (size_t)b * Z_DIM);
    f32x4 zv[4];
#pragma unroll
    for (int p = 0; p < 4; ++p) zv[p] = Z4[p * 16 + l16];

    // ---- layer 1: [64,256] @ z -> h1, relu. Wave w: rows 16w..16w+15 ----
    {
        const f32x4* __restrict__ W = (const f32x4*)(orow + OFF_W1) + (size_t)(w * 16) * 64;
        f32x4 wv[16];
#pragma unroll
        for (int g = 0; g < 4; ++g)
#pragma unroll
            for (int p = 0; p < 4; ++p)
                wv[g * 4 + p] = W[(g * 4 + lg) * 64 + p * 16 + l16];
#pragma unroll
        for (int g = 0; g < 4; ++g) {
            float acc = 0.f;
#pragma unroll
            for (int p = 0; p < 4; ++p) acc += dot4(wv[g * 4 + p], zv[p]);
            acc += __shfl_xor(acc, 1);
            acc += __shfl_xor(acc, 2);
            acc += __shfl_xor(acc, 4);
            acc += __shfl_xor(acc, 8);
            const int r = 16 * w + g * 4 + lg;
            if (l16 == 0) h1[r] = fmaxf(acc + orow[OFF_B1 + r], 0.f);
        }
    }
    __syncthreads();

    // ---- layer 2: [64,64] @ h1 -> h2, relu. Wave w: rows 16w..16w+15 ----
    {
        const f32x4 h1v = *(const f32x4*)(h1 + 4 * l16);
        const f32x4* __restrict__ W = (const f32x4*)(orow + OFF_W2 + w * 16 * 64);
        f32x4 wv[4];
#pragma unroll
        for (int j = 0; j < 4; ++j) wv[j] = W[j * 64 + lane];
#pragma unroll
        for (int j = 0; j < 4; ++j) {
            float p = dot4(wv[j], h1v);
            p += __shfl_xor(p, 1); p += __shfl_xor(p, 2);
            p += __shfl_xor(p, 4); p += __shfl_xor(p, 8);
            const int r = 16 * w + j * 4 + lg;
            if (l16 == 0) h2[r] = fmaxf(p + orow[OFF_B2 + r], 0.f);
        }
    }
    __syncthreads();

    // ---- layer 3: [32,64] @ h2 -> action. Wave w: rows 8w..8w+7 ----
    {
        const f32x4 h2v = *(const f32x4*)(h2 + 4 * l16);
        const f32x4* __restrict__ W = (const f32x4*)(orow + OFF_W3 + w * 8 * 64);
        f32x4 wv[2];
#pragma unroll
        for (int j = 0; j < 2; ++j) wv[j] = W[j * 64 + lane];
#pragma unroll
        for (int j = 0; j < 2; ++j) {
            float p = dot4(wv[j], h2v);
            p += __shfl_xor(p, 1); p += __shfl_xor(p, 2);
            p += __shfl_xor(p, 4); p += __shfl_xor(p, 8);
            const int r = 8 * w + j * 4 + lg;
            if (l16 == 0) out[(size_t)b * OUT_W + 1 + r] = p + orow[OFF_B3 + r];
        }
    }
}

// ---------- kernel 1: gemm1 + w2conv + col0-init + hyper[0:HYP_K1) ----------
__global__ __launch_bounds__(256) void k1_kernel(
    const float* __restrict__ z, const float* __restrict__ opt,
    const float* __restrict__ w1, const float* __restrict__ b1,
    const float* __restrict__ w2, const float* __restrict__ b3,
    __hip_bfloat16* __restrict__ T1, __hip_bfloat16* __restrict__ w2bf,
    float* __restrict__ out)
{
    __shared__ float h1[64], h2[64];
    const int blk = blockIdx.x, t = threadIdx.x;

    if (blk < G_BLOCKS) {
        gemm_tile<Z_DIM, true, true, false>(z, w1, b1, nullptr, T1, nullptr,
                                            blk >> 3, blk & 7, t);
    } else if (blk < G_BLOCKS + CONV_BLOCKS) {
        const int gtid = (blk - G_BLOCKS) * 256 + t;  // 0..16383
        if (gtid < B_SZ) out[(size_t)gtid * OUT_W] = b3[0];  // init value col
#pragma unroll
        for (int i = 0; i < 16; ++i) {
            const int v = gtid + i * 16384;           // float4 index < 262144
            float4 f = ((const float4*)w2)[v];
            short4v s;
            s[0] = f2bf(f.x); s[1] = f2bf(f.y); s[2] = f2bf(f.z); s[3] = f2bf(f.w);
            ((short4v*)w2bf)[v] = s;
        }
    } else {
        hyper_sample(z, opt, out, blk - (G_BLOCKS + CONV_BLOCKS), t, h1, h2);
    }
}

// ---------- kernel 2: gemm2+value + hyper[HYP_K1:B_SZ) ----------
__global__ __launch_bounds__(256) void k2_kernel(
    const float* __restrict__ z, const float* __restrict__ opt,
    const __hip_bfloat16* __restrict__ T1, const __hip_bfloat16* __restrict__ w2bf,
    const float* __restrict__ b2, const float* __restrict__ w3,
    float* __restrict__ out)
{
    __shared__ float h1[64], h2[64];
    const int blk = blockIdx.x, t = threadIdx.x;

    if (blk < G_BLOCKS) {
        gemm_tile<H_DIM, false, false, true>(T1, w2bf, b2, w3, nullptr, out,
                                             blk >> 3, blk & 7, t);
    } else {
        hyper_sample(z, opt, out, HYP_K1 + (blk - G_BLOCKS), t, h1, h2);
    }
}

// ---------- launcher ----------
extern "C" void kernel_launch(void* const* d_in, const int* in_sizes, int n_in,
                              void* d_out, int out_size, void* d_ws, size_t ws_size,
                              hipStream_t stream)
{
    const float* z   = (const float*)d_in[0];
    const float* opt = (const float*)d_in[1];
    const float* w1  = (const float*)d_in[2];
    const float* b1  = (const float*)d_in[3];
    const float* w2  = (const float*)d_in[4];
    const float* b2  = (const float*)d_in[5];
    const float* w3  = (const float*)d_in[6];
    const float* b3  = (const float*)d_in[7];
    float* out = (float*)d_out;

    __hip_bfloat16* T1   = (__hip_bfloat16*)d_ws;  // 8 MB
    __hip_bfloat16* w2bf = (__hip_bfloat16*)((char*)d_ws +
                             (size_t)B_SZ * H_DIM * sizeof(__hip_bfloat16));  // 2 MB

    k1_kernel<<<dim3(G_BLOCKS + CONV_BLOCKS + HYP_K1), dim3(256), 0, stream>>>(
        z, opt, w1, b1, w2, b3, T1, w2bf, out);

    k2_kernel<<<dim3(G_BLOCKS + (B_SZ - HYP_K1)), dim3(256), 0, stream>>>(
        z, opt, T1, w2bf, b2, w3, out);
}

// Round 8
// 117.377 us; speedup vs baseline: 1.4407x; 1.0219x over previous
//
#include <hip/hip_runtime.h>
#include <hip/hip_bf16.h>
#include <cstdint>

// ---------- types / helpers ----------
typedef __attribute__((ext_vector_type(8))) short  short8;
typedef __attribute__((ext_vector_type(8))) __bf16 bf16x8;
typedef __attribute__((ext_vector_type(4))) float  floatx4;
typedef __attribute__((ext_vector_type(4))) float  f32x4;
typedef __attribute__((ext_vector_type(4))) short  short4v;

union Frag { short8 s; bf16x8 b; };

__device__ inline short f2bf(float f) {
    union { float f; unsigned u; } v; v.f = f;
    unsigned r = (v.u + 0x7fffu + ((v.u >> 16) & 1u)) >> 16;  // RNE
    return (short)r;
}
__device__ inline float elu(float x) { return x > 0.f ? x : __expf(x) - 1.f; }

__device__ inline short8 load8_f32_to_bf16(const float* __restrict__ p) {
    float4 f0 = ((const float4*)p)[0];
    float4 f1 = ((const float4*)p)[1];
    short8 r;
    r[0] = f2bf(f0.x); r[1] = f2bf(f0.y); r[2] = f2bf(f0.z); r[3] = f2bf(f0.w);
    r[4] = f2bf(f1.x); r[5] = f2bf(f1.y); r[6] = f2bf(f1.z); r[7] = f2bf(f1.w);
    return r;
}
__device__ inline float dot4(f32x4 a, f32x4 b) {
    return a.x * b.x + a.y * b.y + a.z * b.z + a.w * b.w;
}
// nontemporal: single-use stream, keep out of L1/L2
__device__ inline f32x4 ntload4(const f32x4* __restrict__ p) {
    return __builtin_nontemporal_load(p);
}
__device__ inline float ntload1(const float* __restrict__ p) {
    return __builtin_nontemporal_load(p);
}

// ---------- constants ----------
#define B_SZ   4096
#define Z_DIM  256
#define H_DIM  1024
#define OUT_W  33
// option packing offsets (SIZES = [16384,64,4096,64,2048,32])
#define OFF_W1 0
#define OFF_B1 16384
#define OFF_W2 16448
#define OFF_B2 20544
#define OFF_W3 20608
#define OFF_B3 22656
#define OPT_W  22688

#define HYP_K1 1024                 // hyper samples done in kernel 1
#define G_BLOCKS 256                // 128x128 tiles: (4096/128) x (1024/128)
#define CONV_BLOCKS 64

// XCD-chunked remap for the 256 gemm blocks: dispatch round-robins XCDs
// (xcd = i % 8); give XCD x tiles j in [32x,32x+32) = 4 contiguous bm rows
// x all 8 bn -> per-XCD L2 working set = 1MB A-panel + 2MB B <= 4MB.
__device__ __forceinline__ int xcd_remap(int i) {
    return (i & 7) * 32 + (i >> 3);
}

// ---------- shared 128x128 MFMA gemm tile (4 waves 2x2, 4x4 frags) ----------
template<int KTOT, bool ACONV, bool BCONV, bool VEPI>
__device__ __forceinline__ void gemm_tile(
    const void* __restrict__ Av, const void* __restrict__ Bv,
    const float* __restrict__ bias, const float* __restrict__ w3,
    __hip_bfloat16* __restrict__ T, float* __restrict__ out,
    int bm, int bn, int tid)
{
    const int lane = tid & 63, wid = tid >> 6;
    const int wm = wid >> 1, wn = wid & 1;
    const int m_wave = bm * 128 + wm * 64;
    const int n_wave = bn * 128 + wn * 64;
    const int lr = lane & 15, lk = (lane >> 4) * 8;

    floatx4 acc[4][4] = {};
    for (int k0 = 0; k0 < KTOT; k0 += 32) {
        Frag a[4], bb[4];
#pragma unroll
        for (int sm = 0; sm < 4; ++sm) {
            const size_t off = (size_t)(m_wave + sm * 16 + lr) * KTOT + k0 + lk;
            if constexpr (ACONV) a[sm].s = load8_f32_to_bf16((const float*)Av + off);
            else                 a[sm].s = *(const short8*)((const ushort*)Av + off);
        }
#pragma unroll
        for (int sn = 0; sn < 4; ++sn) {
            const size_t off = (size_t)(n_wave + sn * 16 + lr) * KTOT + k0 + lk;
            if constexpr (BCONV) bb[sn].s = load8_f32_to_bf16((const float*)Bv + off);
            else                 bb[sn].s = *(const short8*)((const ushort*)Bv + off);
        }
#pragma unroll
        for (int sm = 0; sm < 4; ++sm)
#pragma unroll
            for (int sn = 0; sn < 4; ++sn)
                acc[sm][sn] = __builtin_amdgcn_mfma_f32_16x16x32_bf16(
                    a[sm].b, bb[sn].b, acc[sm][sn], 0, 0, 0);
    }

    if constexpr (VEPI) {
        float bias_v[4], w3_v[4];
#pragma unroll
        for (int sn = 0; sn < 4; ++sn) {
            const int n = n_wave + sn * 16 + lr;
            bias_v[sn] = bias[n];
            w3_v[sn]   = w3[n];
        }
#pragma unroll
        for (int sm = 0; sm < 4; ++sm) {
#pragma unroll
            for (int r = 0; r < 4; ++r) {
                float rowsum = 0.f;
#pragma unroll
                for (int sn = 0; sn < 4; ++sn)
                    rowsum += elu(acc[sm][sn][r] + bias_v[sn]) * w3_v[sn];
                rowsum += __shfl_xor(rowsum, 1);
                rowsum += __shfl_xor(rowsum, 2);
                rowsum += __shfl_xor(rowsum, 4);
                rowsum += __shfl_xor(rowsum, 8);
                if (lr == 0) {
                    const int m = m_wave + sm * 16 + (lane >> 4) * 4 + r;
                    atomicAdd(out + (size_t)m * OUT_W, rowsum);
                }
            }
        }
    } else {
#pragma unroll
        for (int sm = 0; sm < 4; ++sm)
#pragma unroll
            for (int sn = 0; sn < 4; ++sn) {
                const int n = n_wave + sn * 16 + lr;
                const float bv = bias[n];
#pragma unroll
                for (int r = 0; r < 4; ++r) {
                    const int m = m_wave + sm * 16 + (lane >> 4) * 4 + r;
                    T[(size_t)m * H_DIM + n] = __float2bfloat16(elu(acc[sm][sn][r] + bv));
                }
            }
    }
}

// ---------- hypernet: block-per-sample, DPP-only reduces, NT stream ----------
__device__ __forceinline__ void hyper_sample(
    const float* __restrict__ z, const float* __restrict__ opt,
    float* __restrict__ out, int b, int tid,
    float* __restrict__ h1, float* __restrict__ h2)
{
    const int lane = tid & 63, w = tid >> 6;
    const int l16 = lane & 15, lg = lane >> 4;
    const float* __restrict__ orow = opt + (size_t)b * OPT_W;

    // preload z slices: zv[p] = z[b][64p + 4*l16 .. +3] (z is reused -> cached)
    const f32x4* __restrict__ Z4 = (const f32x4*)(z + (size_t)b * Z_DIM);
    f32x4 zv[4];
#pragma unroll
    for (int p = 0; p < 4; ++p) zv[p] = Z4[p * 16 + l16];

    // ---- layer 1: [64,256] @ z -> h1, relu. Wave w: rows 16w..16w+15 ----
    {
        const f32x4* __restrict__ W = (const f32x4*)(orow + OFF_W1) + (size_t)(w * 16) * 64;
        f32x4 wv[16];
#pragma unroll
        for (int g = 0; g < 4; ++g)
#pragma unroll
            for (int p = 0; p < 4; ++p)
                wv[g * 4 + p] = ntload4(W + (g * 4 + lg) * 64 + p * 16 + l16);
#pragma unroll
        for (int g = 0; g < 4; ++g) {
            float acc = 0.f;
#pragma unroll
            for (int p = 0; p < 4; ++p) acc += dot4(wv[g * 4 + p], zv[p]);
            acc += __shfl_xor(acc, 1);
            acc += __shfl_xor(acc, 2);
            acc += __shfl_xor(acc, 4);
            acc += __shfl_xor(acc, 8);
            const int r = 16 * w + g * 4 + lg;
            if (l16 == 0) h1[r] = fmaxf(acc + ntload1(orow + OFF_B1 + r), 0.f);
        }
    }
    __syncthreads();

    // ---- layer 2: [64,64] @ h1 -> h2, relu. Wave w: rows 16w..16w+15 ----
    {
        const f32x4 h1v = *(const f32x4*)(h1 + 4 * l16);
        const f32x4* __restrict__ W = (const f32x4*)(orow + OFF_W2 + w * 16 * 64);
        f32x4 wv[4];
#pragma unroll
        for (int j = 0; j < 4; ++j) wv[j] = ntload4(W + j * 64 + lane);
#pragma unroll
        for (int j = 0; j < 4; ++j) {
            float p = dot4(wv[j], h1v);
            p += __shfl_xor(p, 1); p += __shfl_xor(p, 2);
            p += __shfl_xor(p, 4); p += __shfl_xor(p, 8);
            const int r = 16 * w + j * 4 + lg;
            if (l16 == 0) h2[r] = fmaxf(p + ntload1(orow + OFF_B2 + r), 0.f);
        }
    }
    __syncthreads();

    // ---- layer 3: [32,64] @ h2 -> action. Wave w: rows 8w..8w+7 ----
    {
        const f32x4 h2v = *(const f32x4*)(h2 + 4 * l16);
        const f32x4* __restrict__ W = (const f32x4*)(orow + OFF_W3 + w * 8 * 64);
        f32x4 wv[2];
#pragma unroll
        for (int j = 0; j < 2; ++j) wv[j] = ntload4(W + j * 64 + lane);
#pragma unroll
        for (int j = 0; j < 2; ++j) {
            float p = dot4(wv[j], h2v);
            p += __shfl_xor(p, 1); p += __shfl_xor(p, 2);
            p += __shfl_xor(p, 4); p += __shfl_xor(p, 8);
            const int r = 8 * w + j * 4 + lg;
            if (l16 == 0) out[(size_t)b * OUT_W + 1 + r] = p + ntload1(orow + OFF_B3 + r);
        }
    }
}

// ---------- kernel 1: gemm1 + w2conv + col0-init + hyper[0:HYP_K1) ----------
__global__ __launch_bounds__(256) void k1_kernel(
    const float* __restrict__ z, const float* __restrict__ opt,
    const float* __restrict__ w1, const float* __restrict__ b1,
    const float* __restrict__ w2, const float* __restrict__ b3,
    __hip_bfloat16* __restrict__ T1, __hip_bfloat16* __restrict__ w2bf,
    float* __restrict__ out)
{
    __shared__ float h1[64], h2[64];
    const int blk = blockIdx.x, t = threadIdx.x;

    if (blk < G_BLOCKS) {
        const int j = xcd_remap(blk);
        gemm_tile<Z_DIM, true, true, false>(z, w1, b1, nullptr, T1, nullptr,
                                            j >> 3, j & 7, t);
    } else if (blk < G_BLOCKS + CONV_BLOCKS) {
        const int gtid = (blk - G_BLOCKS) * 256 + t;  // 0..16383
        if (gtid < B_SZ) out[(size_t)gtid * OUT_W] = b3[0];  // init value col
#pragma unroll
        for (int i = 0; i < 16; ++i) {
            const int v = gtid + i * 16384;           // float4 index < 262144
            float4 f = ((const float4*)w2)[v];
            short4v s;
            s[0] = f2bf(f.x); s[1] = f2bf(f.y); s[2] = f2bf(f.z); s[3] = f2bf(f.w);
            ((short4v*)w2bf)[v] = s;
        }
    } else {
        hyper_sample(z, opt, out, blk - (G_BLOCKS + CONV_BLOCKS), t, h1, h2);
    }
}

// ---------- kernel 2: gemm2+value + hyper[HYP_K1:B_SZ) ----------
__global__ __launch_bounds__(256) void k2_kernel(
    const float* __restrict__ z, const float* __restrict__ opt,
    const __hip_bfloat16* __restrict__ T1, const __hip_bfloat16* __restrict__ w2bf,
    const float* __restrict__ b2, const float* __restrict__ w3,
    float* __restrict__ out)
{
    __shared__ float h1[64], h2[64];
    const int blk = blockIdx.x, t = threadIdx.x;

    if (blk < G_BLOCKS) {
        const int j = xcd_remap(blk);
        gemm_tile<H_DIM, false, false, true>(T1, w2bf, b2, w3, nullptr, out,
                                             j >> 3, j & 7, t);
    } else {
        hyper_sample(z, opt, out, HYP_K1 + (blk - G_BLOCKS), t, h1, h2);
    }
}

// ---------- launcher ----------
extern "C" void kernel_launch(void* const* d_in, const int* in_sizes, int n_in,
                              void* d_out, int out_size, void* d_ws, size_t ws_size,
                              hipStream_t stream)
{
    const float* z   = (const float*)d_in[0];
    const float* opt = (const float*)d_in[1];
    const float* w1  = (const float*)d_in[2];
    const float* b1  = (const float*)d_in[3];
    const float* w2  = (const float*)d_in[4];
    const float* b2  = (const float*)d_in[5];
    const float* w3  = (const float*)d_in[6];
    const float* b3  = (const float*)d_in[7];
    float* out = (float*)d_out;

    __hip_bfloat16* T1   = (__hip_bfloat16*)d_ws;  // 8 MB
    __hip_bfloat16* w2bf = (__hip_bfloat16*)((char*)d_ws +
                             (size_t)B_SZ * H_DIM * sizeof(__hip_bfloat16));  // 2 MB

    k1_kernel<<<dim3(G_BLOCKS + CONV_BLOCKS + HYP_K1), dim3(256), 0, stream>>>(
        z, opt, w1, b1, w2, b3, T1, w2bf, out);

    k2_kernel<<<dim3(G_BLOCKS + (B_SZ - HYP_K1)), dim3(256), 0, stream>>>(
        z, opt, T1, w2bf, b2, w3, out);
}